// Round 3
// baseline (38.089 us; speedup 1.0000x reference)
//
#include <hip/hip_runtime.h>

// Problem constants (fixed by setup_inputs): B=64, H=W=512, p=8
// nh=nw=64 -> 4096 patches/batch, 64 elems/patch.

// Map float -> order-preserving uint32 (total order matching float compare).
__device__ __forceinline__ unsigned ordf(float f) {
    unsigned u = __float_as_uint(f);
    return u ^ ((u >> 31) ? 0xFFFFFFFFu : 0x80000000u);
}

__global__ void patch_sums_kernel(const float* __restrict__ outp,
                                  const float* __restrict__ tgt,
                                  unsigned long long* __restrict__ packedL,
                                  unsigned long long* __restrict__ packedM) {
    // One block per (batch b, patch-row ph): an 8-row x 512-col band.
    const int bid = blockIdx.x;       // 0..4095
    const int b   = bid >> 6;
    const int ph  = bid & 63;
    const int t   = threadIdx.x;      // 0..255

    // Thread t handles float4 column col4 (fixed across its 4 rows) ->
    // all 16 of its elements belong to patch pw = col4>>1.
    const int col4  = t & 127;        // 0..127 float4 columns of the band
    const int rbase = t >> 7;         // 0 or 1

    const size_t base = ((size_t)b * 512 + (size_t)ph * 8) * 512
                      + (size_t)col4 * 4 + (size_t)rbase * 512;

    // Issue ALL 8 loads before any use: payload lives in 32 VGPRs, giving
    // one vmcnt wait per thread instead of four serialized latencies.
    float4 o[4], g[4];
#pragma unroll
    for (int k = 0; k < 4; ++k)
        o[k] = *reinterpret_cast<const float4*>(outp + base + (size_t)(2 * k) * 512);
#pragma unroll
    for (int k = 0; k < 4; ++k)
        g[k] = *reinterpret_cast<const float4*>(tgt + base + (size_t)(2 * k) * 512);

    float sAbs = 0.f, sT = 0.f;
#pragma unroll
    for (int k = 0; k < 4; ++k) {
        sAbs += fabsf(o[k].x - g[k].x) + fabsf(o[k].y - g[k].y)
              + fabsf(o[k].z - g[k].z) + fabsf(o[k].w - g[k].w);
        sT   += g[k].x + g[k].y + g[k].z + g[k].w;
    }

    __shared__ float sA[256];
    __shared__ float sM[256];
    sA[t] = sAbs;
    sM[t] = sT;
    __syncthreads();

    if (t < 64) {   // exactly one wave
        const int i0 = 2 * t, i1 = 2 * t + 1, i2 = 128 + 2 * t, i3 = 129 + 2 * t;
        float la = sA[i0] + sA[i1] + sA[i2] + sA[i3];   // sum|o-t| over patch
        float lm = sM[i0] + sM[i1] + sM[i2] + sM[i3];   // sum t  over patch
        int   il = ph * 64 + t;                          // patch index in batch
        int   im = il;

        // In-wave butterfly argmax, first-occurrence (smallest index) ties.
#pragma unroll
        for (int s = 32; s > 0; s >>= 1) {
            const float ol = __shfl_xor(la, s);
            const int   oi = __shfl_xor(il, s);
            if (ol > la || (ol == la && oi < il)) { la = ol; il = oi; }
            const float om = __shfl_xor(lm, s);
            const int   oj = __shfl_xor(im, s);
            if (om > lm || (om == lm && oj < im)) { lm = om; im = oj; }
        }

        if (t == 0) {
            // pack: value (orderable) high, (4095 - idx) low -> atomicMax keeps
            // max value, smallest index on ties. Init 0 is a safe lower bound
            // (orderable(finite float) >= 0x00800000).
            const unsigned long long kl =
                ((unsigned long long)ordf(la) << 32) | (unsigned)(4095 - il);
            const unsigned long long km =
                ((unsigned long long)ordf(lm) << 32) | (unsigned)(4095 - im);
            atomicMax(&packedL[b], kl);
            atomicMax(&packedM[b], km);
        }
    }
}

__global__ void finalize_kernel(const unsigned long long* __restrict__ packedL,
                                const unsigned long long* __restrict__ packedM,
                                float* __restrict__ outp) {
    const int t = threadIdx.x;  // 0..63 (one wave)
    const unsigned il = (unsigned)(packedL[t] & 0xFFFFFFFFu);
    const unsigned im = (unsigned)(packedM[t] & 0xFFFFFFFFu);
    int v = (il == im) ? 1 : 0;
#pragma unroll
    for (int s = 32; s > 0; s >>= 1) v += __shfl_down(v, s);
    if (t == 0) {
        const float nt = (float)v;
        outp[0] = 64.0f;        // total_num
        outp[1] = nt;           // num_true
        outp[2] = 64.0f - nt;   // num_false
        outp[3] = nt / 64.0f;   // correctness
    }
}

extern "C" void kernel_launch(void* const* d_in, const int* in_sizes, int n_in,
                              void* d_out, int out_size, void* d_ws, size_t ws_size,
                              hipStream_t stream) {
    const float* outp = (const float*)d_in[0];
    const float* tgt  = (const float*)d_in[1];
    // d_in[2] = patch_size (==8), hardcoded.

    unsigned long long* packedL = (unsigned long long*)d_ws;   // 64 entries
    unsigned long long* packedM = packedL + 64;                // 64 entries

    // Deterministic init each call (harness does not re-poison between replays).
    hipMemsetAsync(d_ws, 0, 128 * sizeof(unsigned long long), stream);

    patch_sums_kernel<<<64 * 64, 256, 0, stream>>>(outp, tgt, packedL, packedM);
    finalize_kernel<<<1, 64, 0, stream>>>(packedL, packedM, (float*)d_out);
}

// Round 4
// 30.852 us; speedup vs baseline: 1.2346x; 1.2346x over previous
//
#include <hip/hip_runtime.h>

// Problem constants (fixed by setup_inputs): B=64, H=W=512, p=8
// nh=nw=64 -> 4096 patches/batch, 64 elems/patch.
// Decomposition: one WAVE per half-band (8 rows x 256 cols) -> 8192 waves.
// No LDS, no __syncthreads, no atomics.

// Map float -> order-preserving uint32 (total order matching float compare).
__device__ __forceinline__ unsigned ordf(float f) {
    unsigned u = __float_as_uint(f);
    return u ^ ((u >> 31) ? 0xFFFFFFFFu : 0x80000000u);
}

__device__ __forceinline__ unsigned long long umax64(unsigned long long a,
                                                     unsigned long long b) {
    return a > b ? a : b;
}

__global__ void patch_sums_kernel(const float* __restrict__ outp,
                                  const float* __restrict__ tgt,
                                  unsigned long long* __restrict__ wsL,
                                  unsigned long long* __restrict__ wsM) {
    const int t   = threadIdx.x;                 // 0..255 (4 waves/block)
    const int wid = blockIdx.x * 4 + (t >> 6);   // 0..8191 half-band id
    const int l   = t & 63;                      // lane

    const int b    = wid >> 7;        // batch
    const int rest = wid & 127;
    const int ph   = rest >> 1;       // patch row 0..63
    const int h    = rest & 1;        // which half of the 512-col band

    // lane l covers float4 column col4 = h*64 + l of the band, all 8 rows.
    const size_t base = ((size_t)b * 512 + (size_t)ph * 8) * 512
                      + (size_t)h * 256 + (size_t)l * 4;
    const float* po = outp + base;
    const float* pt = tgt  + base;

    // Issue ALL 16 loads, then fence: sched_barrier(0) forbids the compiler
    // from sinking loads past it -> full payload in flight (one vmcnt wait).
    float4 o[8], g[8];
#pragma unroll
    for (int r = 0; r < 8; ++r)
        o[r] = *reinterpret_cast<const float4*>(po + (size_t)r * 512);
#pragma unroll
    for (int r = 0; r < 8; ++r)
        g[r] = *reinterpret_cast<const float4*>(pt + (size_t)r * 512);
    __builtin_amdgcn_sched_barrier(0);

    float sAbs = 0.f, sT = 0.f;
#pragma unroll
    for (int r = 0; r < 8; ++r) {
        sAbs += fabsf(o[r].x - g[r].x) + fabsf(o[r].y - g[r].y)
              + fabsf(o[r].z - g[r].z) + fabsf(o[r].w - g[r].w);
        sT   += g[r].x + g[r].y + g[r].z + g[r].w;
    }

    // Lanes l and l^1 hold the two float4 columns of patch (l>>1): combine.
    sAbs += __shfl_xor(sAbs, 1);
    sT   += __shfl_xor(sT, 1);

    const int idx = ph * 64 + h * 32 + (l >> 1);   // patch index in batch

    // Pack (orderable value | 4095-idx): u64 max == argmax w/ first-occurrence
    // tie-break. Duplicate candidates in lane pairs are identical -> harmless.
    unsigned long long kl = ((unsigned long long)ordf(sAbs) << 32)
                          | (unsigned)(4095 - idx);
    unsigned long long km = ((unsigned long long)ordf(sT) << 32)
                          | (unsigned)(4095 - idx);
#pragma unroll
    for (int s = 32; s > 0; s >>= 1) {
        kl = umax64(kl, __shfl_xor(kl, s));
        km = umax64(km, __shfl_xor(km, s));
    }

    if (l == 0) { wsL[wid] = kl; wsM[wid] = km; }
}

__global__ void finalize_kernel(const unsigned long long* __restrict__ wsL,
                                const unsigned long long* __restrict__ wsM,
                                float* __restrict__ outp) {
    const int t    = threadIdx.x;  // 0..255
    const int q    = t >> 2;       // batch 0..63
    const int part = t & 3;        // quarter of this batch's 128 candidates

    unsigned long long ml = 0, mm = 0;
    const int base = q * 128 + part * 32;
    for (int i = 0; i < 32; ++i) {
        ml = umax64(ml, wsL[base + i]);
        mm = umax64(mm, wsM[base + i]);
    }
    // combine the 4 parts (lanes q*4..q*4+3 are in the same wave)
    ml = umax64(ml, __shfl_xor(ml, 1));
    ml = umax64(ml, __shfl_xor(ml, 2));
    mm = umax64(mm, __shfl_xor(mm, 1));
    mm = umax64(mm, __shfl_xor(mm, 2));

    __shared__ int flags[64];
    if (part == 0)
        flags[q] = ((unsigned)(ml & 0xFFFFFFFFu) == (unsigned)(mm & 0xFFFFFFFFu)) ? 1 : 0;
    __syncthreads();

    if (t < 64) {   // one wave sums the 64 agree flags
        int v = flags[t];
#pragma unroll
        for (int s = 32; s > 0; s >>= 1) v += __shfl_down(v, s);
        if (t == 0) {
            const float nt = (float)v;
            outp[0] = 64.0f;        // total_num
            outp[1] = nt;           // num_true
            outp[2] = 64.0f - nt;   // num_false
            outp[3] = nt / 64.0f;   // correctness
        }
    }
}

extern "C" void kernel_launch(void* const* d_in, const int* in_sizes, int n_in,
                              void* d_out, int out_size, void* d_ws, size_t ws_size,
                              hipStream_t stream) {
    const float* outp = (const float*)d_in[0];
    const float* tgt  = (const float*)d_in[1];
    // d_in[2] = patch_size (==8), hardcoded.

    unsigned long long* wsL = (unsigned long long*)d_ws;   // 8192 u64
    unsigned long long* wsM = wsL + 8192;                  // 8192 u64

    patch_sums_kernel<<<2048, 256, 0, stream>>>(outp, tgt, wsL, wsM);
    finalize_kernel<<<1, 256, 0, stream>>>(wsL, wsM, (float*)d_out);
}

// Round 6
// 26.959 us; speedup vs baseline: 1.4128x; 1.1444x over previous
//
#include <hip/hip_runtime.h>

// PatchLoss: B=64, H=W=512, p=8 -> per batch 4096 patches of 64 elems.
// argmax over patches of sum|o-t| vs argmax of sum(t) (mean = sum/64 is
// argmax-invariant). Outputs: {64, num_true, 64-num_true, num_true/64}.
//
// Structure: 512 blocks x 256 thr = 2048 persistent waves. Wave g owns the
// 4 half-bands {ws_ + 32k} of batch g>>5 (half-band = 8 rows x 256 cols,
// one float4 per lane per row). Software-pipelined in plain C: load tile
// k+1 into the idle ping-pong buffer, then consume tile k.
// __launch_bounds__(256, 2) unlocks a 256-VGPR budget so the scheduler's
// occupancy heuristic (which produced VGPR=20/32 and ~6-deep load windows
// in R2-R4) stops sinking the load clusters.

__device__ __forceinline__ unsigned ordf(float f) {
    unsigned u = __float_as_uint(f);
    return u ^ ((u >> 31) ? 0xFFFFFFFFu : 0x80000000u);
}

__device__ __forceinline__ unsigned long long umax64(unsigned long long a,
                                                     unsigned long long b) {
    return a > b ? a : b;
}

__device__ __forceinline__ void loadc(float4 (&O)[8], float4 (&G)[8],
                                      const float* po, const float* pt) {
#pragma unroll
    for (int r = 0; r < 8; ++r)
        O[r] = *reinterpret_cast<const float4*>(po + (size_t)r * 512);
#pragma unroll
    for (int r = 0; r < 8; ++r)
        G[r] = *reinterpret_cast<const float4*>(pt + (size_t)r * 512);
}

__device__ __forceinline__ void consume(const float4 (&O)[8], const float4 (&G)[8],
                                        int ws_, int l, int k,
                                        unsigned long long& kl,
                                        unsigned long long& km) {
    float sA = 0.f, sT = 0.f;
#pragma unroll
    for (int r = 0; r < 8; ++r) {
        sA += fabsf(O[r].x - G[r].x) + fabsf(O[r].y - G[r].y)
            + fabsf(O[r].z - G[r].z) + fabsf(O[r].w - G[r].w);
        sT += G[r].x + G[r].y + G[r].z + G[r].w;
    }
    // lanes l and l^1 hold the two float4 columns of one patch: combine.
    sA += __shfl_xor(sA, 1);
    sT += __shfl_xor(sT, 1);
    const int tb  = ws_ + 32 * k;                                // half-band
    const int idx = (tb >> 1) * 64 + (tb & 1) * 32 + (l >> 1);   // patch idx
    kl = umax64(kl, ((unsigned long long)ordf(sA) << 32) | (unsigned)(4095 - idx));
    km = umax64(km, ((unsigned long long)ordf(sT) << 32) | (unsigned)(4095 - idx));
}

__global__ __launch_bounds__(256, 2)
void patch_kernel(const float* __restrict__ outp,
                  const float* __restrict__ tgt,
                  unsigned long long* __restrict__ wsL,
                  unsigned long long* __restrict__ wsM) {
    const int t   = threadIdx.x;
    const int g   = blockIdx.x * 4 + (t >> 6);   // wave id 0..2047
    const int l   = t & 63;
    const int b   = g >> 5;                      // batch (32 waves/batch)
    const int ws_ = g & 31;                      // wave slot in batch

    // half-band tb = ws_+32k: base = b*512*512 + (tb>>1)*8*512 + (tb&1)*256
    // tile step k->k+1: +16 patch rows = +65536 floats.
    const size_t base0 = (size_t)b * 262144 + (size_t)(ws_ >> 1) * 4096
                       + (size_t)(ws_ & 1) * 256 + (size_t)l * 4;
    const float* po = outp + base0;
    const float* pt = tgt  + base0;

    float4 oA[8], gA[8], oB[8], gB[8];
    unsigned long long kl = 0, km = 0;

    loadc(oA, gA, po,          pt);              // tile0 -> A
    loadc(oB, gB, po + 65536,  pt + 65536);      // tile1 -> B (in flight)
    consume(oA, gA, ws_, l, 0, kl, km);          // consume tile0
    loadc(oA, gA, po + 131072, pt + 131072);     // tile2 -> A (in flight)
    consume(oB, gB, ws_, l, 1, kl, km);          // consume tile1
    loadc(oB, gB, po + 196608, pt + 196608);     // tile3 -> B (in flight)
    consume(oA, gA, ws_, l, 2, kl, km);          // consume tile2
    consume(oB, gB, ws_, l, 3, kl, km);          // consume tile3

    // per-wave butterfly argmax (all candidates are same-batch)
#pragma unroll
    for (int s = 32; s > 1; s >>= 1) {    // s=1 skipped: lane pairs identical
        kl = umax64(kl, __shfl_xor(kl, s));
        km = umax64(km, __shfl_xor(km, s));
    }

    if (l == 0) { wsL[g] = kl; wsM[g] = km; }
}

__global__ void finalize_kernel(const unsigned long long* __restrict__ wsL,
                                const unsigned long long* __restrict__ wsM,
                                float* __restrict__ outp) {
    const int t    = threadIdx.x;  // 0..255
    const int q    = t >> 2;       // batch
    const int part = t & 3;

    unsigned long long ml = 0, mm = 0;
    const int base = q * 32 + part * 8;
#pragma unroll
    for (int i = 0; i < 8; ++i) {
        ml = umax64(ml, wsL[base + i]);
        mm = umax64(mm, wsM[base + i]);
    }
    ml = umax64(ml, __shfl_xor(ml, 1));
    ml = umax64(ml, __shfl_xor(ml, 2));
    mm = umax64(mm, __shfl_xor(mm, 1));
    mm = umax64(mm, __shfl_xor(mm, 2));

    __shared__ int flags[64];
    if (part == 0)
        flags[q] = ((unsigned)ml == (unsigned)mm) ? 1 : 0;  // low32: 4095-idx
    __syncthreads();

    if (t < 64) {
        int v = flags[t];
#pragma unroll
        for (int s = 32; s > 0; s >>= 1) v += __shfl_down(v, s);
        if (t == 0) {
            const float nt = (float)v;
            outp[0] = 64.0f;
            outp[1] = nt;
            outp[2] = 64.0f - nt;
            outp[3] = nt / 64.0f;
        }
    }
}

extern "C" void kernel_launch(void* const* d_in, const int* in_sizes, int n_in,
                              void* d_out, int out_size, void* d_ws, size_t ws_size,
                              hipStream_t stream) {
    const float* outp = (const float*)d_in[0];
    const float* tgt  = (const float*)d_in[1];
    // d_in[2] = patch_size (==8), hardcoded.

    unsigned long long* wsL = (unsigned long long*)d_ws;   // 2048 u64
    unsigned long long* wsM = wsL + 2048;                  // 2048 u64

    patch_kernel<<<512, 256, 0, stream>>>(outp, tgt, wsL, wsM);
    finalize_kernel<<<1, 256, 0, stream>>>(wsL, wsM, (float*)d_out);
}